// Round 3
// baseline (178.704 us; speedup 1.0000x reference)
//
#include <hip/hip_runtime.h>

#define D 64

// ---------------------------------------------------------------------------
// K1: Y[i][:] = bf16( deg[i] * (X[i][:] @ W) )  — one wave per node.
// node is forced wave-uniform (readfirstlane) so X-row and deg reads become
// s_load (scalar path); W column lives in 64 VGPRs; inner loop is pure
// v_fmac with SGPR multiplier. 4 split accumulators break the dep chain.
// ---------------------------------------------------------------------------
__global__ __launch_bounds__(256, 4)
void gcn_xw_mv(const float* __restrict__ X, const float* __restrict__ W,
               const float* __restrict__ deg, ushort* __restrict__ Y,
               int n_nodes)
{
    const int lane   = threadIdx.x & 63;
    const int gwave  = __builtin_amdgcn_readfirstlane(
                          (int)((blockIdx.x * blockDim.x + threadIdx.x) >> 6));
    const int nwaves = (int)((gridDim.x * blockDim.x) >> 6);

    float w[D];
#pragma unroll
    for (int l = 0; l < D; ++l) w[l] = W[l * D + lane];

    for (int node = gwave; node < n_nodes; node += nwaves) {
        const float* __restrict__ xr = X + (size_t)node * D;   // uniform -> s_load
        float a0 = 0.f, a1 = 0.f, a2 = 0.f, a3 = 0.f;
#pragma unroll
        for (int l = 0; l < D; l += 4) {
            a0 = fmaf(xr[l + 0], w[l + 0], a0);
            a1 = fmaf(xr[l + 1], w[l + 1], a1);
            a2 = fmaf(xr[l + 2], w[l + 2], a2);
            a3 = fmaf(xr[l + 3], w[l + 3], a3);
        }
        const float r = ((a0 + a1) + (a2 + a3)) * deg[node];
        const uint32_t u = __float_as_uint(r);         // fp32 -> bf16 RNE
        Y[(size_t)node * D + lane] = (ushort)((u + 0x7fffu + ((u >> 16) & 1u)) >> 16);
    }
}

// ---------------------------------------------------------------------------
// K2: out[i][:] = deg[i] * sum_e Y[col[e]][:]  — 4 nodes per wave, no
// cross-lane ops. lane = (slot s = lane>>4 -> node, chunk f = lane&15 ->
// features [4f,4f+4)). Each lane owns its node's 16 edge indices (4 dwordx4
// loads), issues 16 independent dwordx2 row loads (each instr covers 4 full
// 128B rows), accumulates 4 fp32, stores one float4 (1KB/instr wave store).
// ---------------------------------------------------------------------------
__global__ __launch_bounds__(256, 4)
void gcn_gather4(const ushort* __restrict__ Y, const int* __restrict__ rp,
                 const int* __restrict__ col, const float* __restrict__ deg,
                 float* __restrict__ out, int n_nodes)
{
    const int lane   = threadIdx.x & 63;
    const int s      = lane >> 4;        // node slot within wave
    const int f      = lane & 15;        // feature chunk
    const int gwave  = (int)((blockIdx.x * blockDim.x + threadIdx.x) >> 6);
    const int nwaves = (int)((gridDim.x * blockDim.x) >> 6);
    const int ngroups = (n_nodes + 3) >> 2;

    for (int g = gwave; g < ngroups; g += nwaves) {
        const int  n     = g * 4 + s;
        const bool valid = (n < n_nodes);
        const int  rpn   = valid ? rp[n]     : 0;
        const int  rpe   = valid ? rp[n + 1] : 0;
        const int  dcnt  = rpe - rpn;

        const bool ok = !valid || (dcnt == 16 && (rpn & 3) == 0);
        if (__ballot(ok) == ~0ull) {
            // fast path: degree 16 everywhere (this dataset)
            int idx[16];
            *(int4*)(idx + 0)  = *(const int4*)(col + rpn + 0);
            *(int4*)(idx + 4)  = *(const int4*)(col + rpn + 4);
            *(int4*)(idx + 8)  = *(const int4*)(col + rpn + 8);
            *(int4*)(idx + 12) = *(const int4*)(col + rpn + 12);

            float a0 = 0.f, a1 = 0.f, a2 = 0.f, a3 = 0.f;
#pragma unroll
            for (int j = 0; j < 16; ++j) {
                const uint2 u = *(const uint2*)(Y + ((size_t)idx[j] << 6) + (f << 2));
                a0 += __uint_as_float(u.x << 16);
                a1 += __uint_as_float(u.x & 0xffff0000u);
                a2 += __uint_as_float(u.y << 16);
                a3 += __uint_as_float(u.y & 0xffff0000u);
            }
            if (valid) {
                const float dn = deg[n];
                float4 v;
                v.x = a0 * dn; v.y = a1 * dn; v.z = a2 * dn; v.w = a3 * dn;
                *(float4*)(out + (size_t)n * D + f * 4) = v;
            }
        } else if (valid) {
            // generic fallback: per-lane loop over its node's edges
            float a0 = 0.f, a1 = 0.f, a2 = 0.f, a3 = 0.f;
            for (int e = rpn; e < rpe; ++e) {
                const int sj = col[e];
                const uint2 u = *(const uint2*)(Y + ((size_t)sj << 6) + (f << 2));
                a0 += __uint_as_float(u.x << 16);
                a1 += __uint_as_float(u.x & 0xffff0000u);
                a2 += __uint_as_float(u.y << 16);
                a3 += __uint_as_float(u.y & 0xffff0000u);
            }
            const float dn = deg[n];
            float4 v;
            v.x = a0 * dn; v.y = a1 * dn; v.z = a2 * dn; v.w = a3 * dn;
            *(float4*)(out + (size_t)n * D + f * 4) = v;
        }
    }
}

// ---------------------------------------------------------------------------
// Fallback (ws too small): round-1 fused kernel, fp32 end-to-end.
// ---------------------------------------------------------------------------
static __device__ __forceinline__ float bcast_f(float v, int l) {
    return __uint_as_float(__builtin_amdgcn_readlane(__float_as_uint(v), l));
}

__global__ __launch_bounds__(256, 4)
void gcn_fused_kernel(const float* __restrict__ X, const float* __restrict__ W,
                      const int* __restrict__ rp, const int* __restrict__ col,
                      const float* __restrict__ deg, float* __restrict__ out,
                      int n_nodes)
{
    const int lane   = threadIdx.x & 63;
    const int gwave  = (int)((blockIdx.x * blockDim.x + threadIdx.x) >> 6);
    const int nwaves = (int)((gridDim.x * blockDim.x) >> 6);

    for (int node = gwave; node < n_nodes; node += nwaves) {
        const int start = rp[node];
        const int end   = rp[node + 1];
        const float di  = deg[node];
        float h = 0.f;

        for (int e0 = start; e0 < end; e0 += 64) {
            const int cnt = min(64, end - e0);
            int   s_  = (lane < cnt) ? col[e0 + lane] : 0;
            float nm_ = (lane < cnt) ? di * deg[s_] : 0.f;
            for (int j = 0; j < cnt; ++j) {
                const int   sj = __builtin_amdgcn_readlane(s_, j);
                const float nj = bcast_f(nm_, j);
                h = fmaf(nj, X[(size_t)sj * D + lane], h);
            }
        }

        float c0 = 0.f, c1 = 0.f, c2 = 0.f, c3 = 0.f;
#pragma unroll
        for (int l = 0; l < D; l += 4) {
            c0 = fmaf(bcast_f(h, l + 0), W[(l + 0) * D + lane], c0);
            c1 = fmaf(bcast_f(h, l + 1), W[(l + 1) * D + lane], c1);
            c2 = fmaf(bcast_f(h, l + 2), W[(l + 2) * D + lane], c2);
            c3 = fmaf(bcast_f(h, l + 3), W[(l + 3) * D + lane], c3);
        }
        out[(size_t)node * D + lane] = (c0 + c1) + (c2 + c3);
    }
}

extern "C" void kernel_launch(void* const* d_in, const int* in_sizes, int n_in,
                              void* d_out, int out_size, void* d_ws, size_t ws_size,
                              hipStream_t stream) {
    const float* X   = (const float*)d_in[0];
    const float* W   = (const float*)d_in[1];
    const int*   rp  = (const int*)d_in[2];
    const int*   col = (const int*)d_in[3];
    const float* deg = (const float*)d_in[4];
    float* out = (float*)d_out;

    const int n_nodes = in_sizes[4];   // degrees: one per node
    const size_t y_bytes = (size_t)n_nodes * D * sizeof(ushort);

    if (ws_size >= y_bytes) {
        ushort* Y = (ushort*)d_ws;
        gcn_xw_mv<<<1024, 256, 0, stream>>>(X, W, deg, Y, n_nodes);
        gcn_gather4<<<2048, 256, 0, stream>>>(Y, rp, col, deg, out, n_nodes);
    } else {
        gcn_fused_kernel<<<1024, 256, 0, stream>>>(X, W, rp, col, deg, out, n_nodes);
    }
}

// Round 4
// 130.907 us; speedup vs baseline: 1.3651x; 1.3651x over previous
//
#include <hip/hip_runtime.h>

#define D 64

static __device__ __forceinline__ unsigned int bf16r(float f) {
    const unsigned int u = __float_as_uint(f);
    return (u + 0x7fffu + ((u >> 16) & 1u)) >> 16;   // RNE fp32->bf16
}

// ---------------------------------------------------------------------------
// K1: Y = bf16( deg ⊙ (X @ W) ) — LDS-tiled fp32 GEMM.
// Block = 256 thr, tile = 128 nodes x 64 feats, K=64 (single K-tile: load,
// sync, compute, store). Xs is stored transposed [k][m] (stride 132 keeps
// b128 alignment + conflict-free reads); Ws is a direct copy [k][n].
// Thread (ty=t>>4, tx=t&15) computes nodes 8ty..+7, feats 4tx..+3 (32 accs).
// Per k: 3x ds_read_b128 + 32 v_fma -> VALU-bound.
// ---------------------------------------------------------------------------
__global__ __launch_bounds__(256, 2)
void gcn_xw_tile(const float* __restrict__ X, const float* __restrict__ W,
                 const float* __restrict__ deg, ushort* __restrict__ Y,
                 int n_nodes)
{
    __shared__ float Xs[64][132];   // [k][m], +4 pad: 16B-aligned rows
    __shared__ float Ws[64][64];    // [k][n], same layout as global

    const int t  = threadIdx.x;
    const int m0 = blockIdx.x * 128;

    // ---- load W: 4096 floats = 1024 float4, linear copy (coalesced) ----
    {
        const float4* __restrict__ W4 = (const float4*)W;
        float4* Ws4 = (float4*)&Ws[0][0];
#pragma unroll
        for (int r = 0; r < 4; ++r) Ws4[t + 256 * r] = W4[t + 256 * r];
    }

    // ---- load X tile, transposed into Xs[k][m] ----
#pragma unroll
    for (int r = 0; r < 8; ++r) {
        const int q   = t + 256 * r;
        const int m   = q >> 4;        // 0..127  node within tile
        const int kg  = q & 15;        // float4 column group
        const int row = m0 + m;
        float4 xv = make_float4(0.f, 0.f, 0.f, 0.f);
        if (row < n_nodes) xv = ((const float4*)(X + (size_t)row * D))[kg];
        Xs[4 * kg + 0][m] = xv.x;
        Xs[4 * kg + 1][m] = xv.y;
        Xs[4 * kg + 2][m] = xv.z;
        Xs[4 * kg + 3][m] = xv.w;
    }
    __syncthreads();

    const int tx = t & 15;             // feats 4tx..4tx+3
    const int ty = t >> 4;             // nodes 8ty..8ty+7

    float acc[8][4];
#pragma unroll
    for (int i = 0; i < 8; ++i)
#pragma unroll
        for (int j = 0; j < 4; ++j) acc[i][j] = 0.f;

#pragma unroll 8
    for (int k = 0; k < 64; ++k) {
        const float4 wv = *(const float4*)&Ws[k][4 * tx];
        const float4 xa = *(const float4*)&Xs[k][8 * ty];
        const float4 xb = *(const float4*)&Xs[k][8 * ty + 4];
#define ROWFMA(i, xs)                                   \
        acc[i][0] = fmaf(xs, wv.x, acc[i][0]);          \
        acc[i][1] = fmaf(xs, wv.y, acc[i][1]);          \
        acc[i][2] = fmaf(xs, wv.z, acc[i][2]);          \
        acc[i][3] = fmaf(xs, wv.w, acc[i][3]);
        ROWFMA(0, xa.x) ROWFMA(1, xa.y) ROWFMA(2, xa.z) ROWFMA(3, xa.w)
        ROWFMA(4, xb.x) ROWFMA(5, xb.y) ROWFMA(6, xb.z) ROWFMA(7, xb.w)
#undef ROWFMA
    }

    // ---- epilogue: scale by deg, round to bf16, store 8B per node ----
#pragma unroll
    for (int i = 0; i < 8; ++i) {
        const int node = m0 + 8 * ty + i;
        if (node < n_nodes) {
            const float dn = deg[node];
            uint2 v;
            v.x = bf16r(acc[i][0] * dn) | (bf16r(acc[i][1] * dn) << 16);
            v.y = bf16r(acc[i][2] * dn) | (bf16r(acc[i][3] * dn) << 16);
            *(uint2*)(Y + (size_t)node * D + 4 * tx) = v;
        }
    }
}

// ---------------------------------------------------------------------------
// K2: out[i][:] = deg[i] * sum_e Y[col[e]][:]  — 4 nodes per wave, no
// cross-lane ops. lane = (slot s=lane>>4 -> node, chunk f=lane&15 ->
// features [4f,4f+4)). Each lane owns its node's 16 edge indices (4 dwordx4
// loads), 16 independent dwordx2 row loads (each instr = 4 full 128B rows),
// accumulates 4 fp32, stores one float4 (1KB/instr wave store).
// ---------------------------------------------------------------------------
__global__ __launch_bounds__(256, 4)
void gcn_gather4(const ushort* __restrict__ Y, const int* __restrict__ rp,
                 const int* __restrict__ col, const float* __restrict__ deg,
                 float* __restrict__ out, int n_nodes)
{
    const int lane   = threadIdx.x & 63;
    const int s      = lane >> 4;
    const int f      = lane & 15;
    const int gwave  = (int)((blockIdx.x * blockDim.x + threadIdx.x) >> 6);
    const int nwaves = (int)((gridDim.x * blockDim.x) >> 6);
    const int ngroups = (n_nodes + 3) >> 2;

    for (int g = gwave; g < ngroups; g += nwaves) {
        const int  n     = g * 4 + s;
        const bool valid = (n < n_nodes);
        const int  rpn   = valid ? rp[n]     : 0;
        const int  rpe   = valid ? rp[n + 1] : 0;
        const int  dcnt  = rpe - rpn;

        const bool ok = !valid || (dcnt == 16 && (rpn & 3) == 0);
        if (__ballot(ok) == ~0ull) {
            int idx[16];
            *(int4*)(idx + 0)  = *(const int4*)(col + rpn + 0);
            *(int4*)(idx + 4)  = *(const int4*)(col + rpn + 4);
            *(int4*)(idx + 8)  = *(const int4*)(col + rpn + 8);
            *(int4*)(idx + 12) = *(const int4*)(col + rpn + 12);

            float a0 = 0.f, a1 = 0.f, a2 = 0.f, a3 = 0.f;
#pragma unroll
            for (int j = 0; j < 16; ++j) {
                const uint2 u = *(const uint2*)(Y + ((size_t)idx[j] << 6) + (f << 2));
                a0 += __uint_as_float(u.x << 16);
                a1 += __uint_as_float(u.x & 0xffff0000u);
                a2 += __uint_as_float(u.y << 16);
                a3 += __uint_as_float(u.y & 0xffff0000u);
            }
            if (valid) {
                const float dn = deg[n];
                float4 v;
                v.x = a0 * dn; v.y = a1 * dn; v.z = a2 * dn; v.w = a3 * dn;
                *(float4*)(out + (size_t)n * D + f * 4) = v;
            }
        } else if (valid) {
            float a0 = 0.f, a1 = 0.f, a2 = 0.f, a3 = 0.f;
            for (int e = rpn; e < rpe; ++e) {
                const int sj = col[e];
                const uint2 u = *(const uint2*)(Y + ((size_t)sj << 6) + (f << 2));
                a0 += __uint_as_float(u.x << 16);
                a1 += __uint_as_float(u.x & 0xffff0000u);
                a2 += __uint_as_float(u.y << 16);
                a3 += __uint_as_float(u.y & 0xffff0000u);
            }
            const float dn = deg[n];
            float4 v;
            v.x = a0 * dn; v.y = a1 * dn; v.z = a2 * dn; v.w = a3 * dn;
            *(float4*)(out + (size_t)n * D + f * 4) = v;
        }
    }
}

// ---------------------------------------------------------------------------
// Fallback (ws too small): round-1 fused kernel, fp32 end-to-end.
// ---------------------------------------------------------------------------
static __device__ __forceinline__ float bcast_f(float v, int l) {
    return __uint_as_float(__builtin_amdgcn_readlane(__float_as_uint(v), l));
}

__global__ __launch_bounds__(256, 4)
void gcn_fused_kernel(const float* __restrict__ X, const float* __restrict__ W,
                      const int* __restrict__ rp, const int* __restrict__ col,
                      const float* __restrict__ deg, float* __restrict__ out,
                      int n_nodes)
{
    const int lane   = threadIdx.x & 63;
    const int gwave  = (int)((blockIdx.x * blockDim.x + threadIdx.x) >> 6);
    const int nwaves = (int)((gridDim.x * blockDim.x) >> 6);

    for (int node = gwave; node < n_nodes; node += nwaves) {
        const int start = rp[node];
        const int end   = rp[node + 1];
        const float di  = deg[node];
        float h = 0.f;

        for (int e0 = start; e0 < end; e0 += 64) {
            const int cnt = min(64, end - e0);
            int   s_  = (lane < cnt) ? col[e0 + lane] : 0;
            float nm_ = (lane < cnt) ? di * deg[s_] : 0.f;
            for (int j = 0; j < cnt; ++j) {
                const int   sj = __builtin_amdgcn_readlane(s_, j);
                const float nj = bcast_f(nm_, j);
                h = fmaf(nj, X[(size_t)sj * D + lane], h);
            }
        }

        float c0 = 0.f, c1 = 0.f, c2 = 0.f, c3 = 0.f;
#pragma unroll
        for (int l = 0; l < D; l += 4) {
            c0 = fmaf(bcast_f(h, l + 0), W[(l + 0) * D + lane], c0);
            c1 = fmaf(bcast_f(h, l + 1), W[(l + 1) * D + lane], c1);
            c2 = fmaf(bcast_f(h, l + 2), W[(l + 2) * D + lane], c2);
            c3 = fmaf(bcast_f(h, l + 3), W[(l + 3) * D + lane], c3);
        }
        out[(size_t)node * D + lane] = (c0 + c1) + (c2 + c3);
    }
}

extern "C" void kernel_launch(void* const* d_in, const int* in_sizes, int n_in,
                              void* d_out, int out_size, void* d_ws, size_t ws_size,
                              hipStream_t stream) {
    const float* X   = (const float*)d_in[0];
    const float* W   = (const float*)d_in[1];
    const int*   rp  = (const int*)d_in[2];
    const int*   col = (const int*)d_in[3];
    const float* deg = (const float*)d_in[4];
    float* out = (float*)d_out;

    const int n_nodes = in_sizes[4];   // degrees: one per node
    const size_t y_bytes = (size_t)n_nodes * D * sizeof(ushort);

    if (ws_size >= y_bytes) {
        ushort* Y = (ushort*)d_ws;
        const int k1_blocks = (n_nodes + 127) / 128;
        gcn_xw_tile<<<k1_blocks, 256, 0, stream>>>(X, W, deg, Y, n_nodes);
        gcn_gather4<<<2048, 256, 0, stream>>>(Y, rp, col, deg, out, n_nodes);
    } else {
        gcn_fused_kernel<<<1024, 256, 0, stream>>>(X, W, rp, col, deg, out, n_nodes);
    }
}